// Round 1
// baseline (99.081 us; speedup 1.0000x reference)
//
#include <hip/hip_runtime.h>

// ALCOVE RBF: out[b,e] = exp(-C * sum_d attn[d] * |E[e,d] - X[b,d]|)
// BATCH=2048, NE=2048, ND=128, f32 in/out.
//
// attn >= 0 (uniform(0,1)/128), so attn_d*|x-e| == |attn_d*x - attn_d*e|:
// pre-scale X and E by attn while staging into LDS, making the inner loop
// pure sub + add-with-abs-modifier (2 VALU/term — the fp32 issue floor).
//
// Tiles staged TRANSPOSED in LDS ([d][row]) so the lane-varying index is
// contiguous -> conflict-free ds_read_b128. (Row-major [row][d] cannot be
// conflict-free for b128: padding must stay a multiple of 4 floats for 16B
// alignment, which forces row-stride % 32 banks into {0,4*even} patterns.)

#define BATCH 2048
#define NE 2048
#define ND 128
#define CCONST 6.5f

#define TB 128   // batch tile rows
#define TE 64    // exemplar tile rows
#define KC 64    // dim chunk resident in LDS

__global__ __launch_bounds__(256, 2)
void alcove_rbf_kernel(const float* __restrict__ X,
                       const float* __restrict__ E,
                       const float* __restrict__ A,
                       float* __restrict__ out) {
  __shared__ float Xs[KC * TB];  // [d][b]  32 KB
  __shared__ float Es[KC * TE];  // [d][e]  16 KB

  const int tid = threadIdx.x;
  const int e0 = blockIdx.x * TE;   // 32 tiles
  const int b0 = blockIdx.y * TB;   // 16 tiles

  const int tx = tid & 15;   // exemplar dir: 4 e's per thread (4*tx .. +3)
  const int ty = tid >> 4;   // batch dir:    8 b's per thread (8*ty .. +7)

  float acc[8][4];
#pragma unroll
  for (int j = 0; j < 8; ++j)
#pragma unroll
    for (int i = 0; i < 4; ++i) acc[j][i] = 0.f;

  const int lane_in = tid & 3;

  for (int kc = 0; kc < ND; kc += KC) {
    if (kc) __syncthreads();

    // ---- stage X tile: TB rows x KC dims, transposed into Xs[d][b] ----
    // 4 consecutive lanes take 4 consecutive float4 chunks of one row
    // (64B coalesced global); LDS write is 4-way conflict (mild, staging
    // is ~1% of kernel time).
#pragma unroll
    for (int it = 0; it < 8; ++it) {
      int g = (it * 256 + tid) >> 2;      // 64B-group id, 0..511
      int row = g & (TB - 1);
      int gc = g >> 7;                    // 0..3
      int c4 = 4 * gc + lane_in;          // float4 index within chunk, 0..15
      float4 v = reinterpret_cast<const float4*>(X + (size_t)(b0 + row) * ND + kc)[c4];
      float4 a = reinterpret_cast<const float4*>(A + kc)[c4];
      int dbase = 4 * c4;
      Xs[(dbase + 0) * TB + row] = v.x * a.x;
      Xs[(dbase + 1) * TB + row] = v.y * a.y;
      Xs[(dbase + 2) * TB + row] = v.z * a.z;
      Xs[(dbase + 3) * TB + row] = v.w * a.w;
    }
    // ---- stage E tile: TE rows x KC dims, transposed into Es[d][e] ----
#pragma unroll
    for (int it = 0; it < 4; ++it) {
      int g = (it * 256 + tid) >> 2;      // 0..255
      int row = g & (TE - 1);
      int gc = g >> 6;                    // 0..3
      int c4 = 4 * gc + lane_in;
      float4 v = reinterpret_cast<const float4*>(E + (size_t)(e0 + row) * ND + kc)[c4];
      float4 a = reinterpret_cast<const float4*>(A + kc)[c4];
      int dbase = 4 * c4;
      Es[(dbase + 0) * TE + row] = v.x * a.x;
      Es[(dbase + 1) * TE + row] = v.y * a.y;
      Es[(dbase + 2) * TE + row] = v.z * a.z;
      Es[(dbase + 3) * TE + row] = v.w * a.w;
    }
    __syncthreads();

    const float4* Xs4 = reinterpret_cast<const float4*>(Xs);
    const float4* Es4 = reinterpret_cast<const float4*>(Es);
#pragma unroll 4
    for (int d = 0; d < KC; ++d) {
      // lanes: Es4 index contiguous across tx (conflict-free);
      // Xs4 index broadcast across 16 lanes per ty value.
      float4 xa = Xs4[d * (TB / 4) + 2 * ty];
      float4 xb = Xs4[d * (TB / 4) + 2 * ty + 1];
      float4 ev = Es4[d * (TE / 4) + tx];
      float xv[8] = {xa.x, xa.y, xa.z, xa.w, xb.x, xb.y, xb.z, xb.w};
      float ew[4] = {ev.x, ev.y, ev.z, ev.w};
#pragma unroll
      for (int j = 0; j < 8; ++j)
#pragma unroll
        for (int i = 0; i < 4; ++i)
          acc[j][i] += fabsf(xv[j] - ew[i]);  // v_sub + v_add w/ |.| modifier
    }
  }

  // ---- epilogue: exp and coalesced float4 stores ----
#pragma unroll
  for (int j = 0; j < 8; ++j) {
    int b = b0 + 8 * ty + j;
    float4 o;
    o.x = __expf(-CCONST * acc[j][0]);
    o.y = __expf(-CCONST * acc[j][1]);
    o.z = __expf(-CCONST * acc[j][2]);
    o.w = __expf(-CCONST * acc[j][3]);
    reinterpret_cast<float4*>(out + (size_t)b * NE + e0)[tx] = o;
  }
}

extern "C" void kernel_launch(void* const* d_in, const int* in_sizes, int n_in,
                              void* d_out, int out_size, void* d_ws, size_t ws_size,
                              hipStream_t stream) {
  const float* X = (const float*)d_in[0];   // inputs    (2048,128)
  const float* E = (const float*)d_in[1];   // exemplars (2048,128)
  const float* A = (const float*)d_in[2];   // attn      (128,)
  float* out = (float*)d_out;               // (2048,2048)

  dim3 grid(NE / TE, BATCH / TB);           // (32,16) = 512 blocks = 2/CU
  dim3 block(256);
  alcove_rbf_kernel<<<grid, block, 0, stream>>>(X, E, A, out);
}

// Round 2
// 81.938 us; speedup vs baseline: 1.2092x; 1.2092x over previous
//
#include <hip/hip_runtime.h>
#include <stdint.h>

// ALCOVE RBF: out[b,e] = exp(-C * sum_d attn[d] * |E[e,d] - X[b,d]|)
// BATCH=2048, NE=2048, ND=128, f32 in/out.
//
// R2: v_sad_u32 fixed-point inner loop (1 VALU op per term) + 4 blocks/CU.
//
// attn >= 0, so attn_d*|x-e| == |attn_d*x - attn_d*e|. Quantize the
// attn-scaled operands to biased fixed point during LDS staging:
//     q(v) = (uint)(v * 2^24 + (2^21 + 0.5))
// |attn*x| <= ~6/128 -> |v*2^24| < 2^20 << bias 2^21 (stays positive);
// sum of 128 |diffs| < 2^29 (no u32 overflow). Bias cancels in |a-b|.
// Quantization error on dist <= ~1e-5 -> output error ~7e-5 << 1.7e-3 thr.
// Inner loop: one v_sad_u32 (|a-b|+c) per term = the 1-op/term floor.

#define BATCH 2048
#define NE 2048
#define ND 128

#define TB 64    // batch tile
#define TE 64    // exemplar tile
#define KC 64    // dim chunk in LDS

#define QSCALE 16777216.0f            // 2^24
#define QBIAS  2097152.5f             // 2^21 + 0.5 (trunc -> round-ish)
#define KEXP   (-6.5f / 16777216.0f)  // -C / 2^24

#define SAD(acc, a, b) asm("v_sad_u32 %0, %1, %2, %0" : "+v"(acc) : "v"(a), "v"(b))

__global__ __launch_bounds__(256, 4)
void alcove_rbf_kernel(const float* __restrict__ X,
                       const float* __restrict__ E,
                       const float* __restrict__ A,
                       float* __restrict__ out) {
  __shared__ uint32_t Xs[KC * TB];  // [d][b]  16 KB
  __shared__ uint32_t Es[KC * TE];  // [d][e]  16 KB

  const int tid = threadIdx.x;
  const int e0 = blockIdx.x * TE;   // 32 tiles
  const int b0 = blockIdx.y * TB;   // 32 tiles

  const int tx = tid & 15;          // e dir: 4 e's (4*tx..+3)
  const int ty = tid >> 4;          // b dir: 4 b's (4*ty..+3)
  const int lane_in = tid & 3;

  uint32_t acc[4][4];
#pragma unroll
  for (int j = 0; j < 4; ++j)
#pragma unroll
    for (int i = 0; i < 4; ++i) acc[j][i] = 0u;

  for (int kc = 0; kc < ND; kc += KC) {
    if (kc) __syncthreads();

    const float4* A4 = reinterpret_cast<const float4*>(A + kc);

    // Stage X and E tiles (64 rows x KC dims each), transposed to [d][row],
    // quantizing to biased fixed point. 4 consecutive lanes take 4
    // consecutive float4s of one row (64B coalesced); transposed LDS writes
    // are 4-way bank conflicted (staging is ~2% of inner-loop work).
#pragma unroll
    for (int it = 0; it < 4; ++it) {
      int g = it * 64 + (tid >> 2);     // 0..255
      int row = g & (TB - 1);
      int c4 = 4 * (g >> 6) + lane_in;  // float4 chunk 0..15
      float4 a = A4[c4];
      float4 as;                        // attn * 2^24
      as.x = a.x * QSCALE; as.y = a.y * QSCALE;
      as.z = a.z * QSCALE; as.w = a.w * QSCALE;
      int dbase = 4 * c4;

      float4 vx = reinterpret_cast<const float4*>(X + (size_t)(b0 + row) * ND + kc)[c4];
      Xs[(dbase + 0) * TB + row] = (uint32_t)fmaf(vx.x, as.x, QBIAS);
      Xs[(dbase + 1) * TB + row] = (uint32_t)fmaf(vx.y, as.y, QBIAS);
      Xs[(dbase + 2) * TB + row] = (uint32_t)fmaf(vx.z, as.z, QBIAS);
      Xs[(dbase + 3) * TB + row] = (uint32_t)fmaf(vx.w, as.w, QBIAS);

      float4 ve = reinterpret_cast<const float4*>(E + (size_t)(e0 + row) * ND + kc)[c4];
      Es[(dbase + 0) * TE + row] = (uint32_t)fmaf(ve.x, as.x, QBIAS);
      Es[(dbase + 1) * TE + row] = (uint32_t)fmaf(ve.y, as.y, QBIAS);
      Es[(dbase + 2) * TE + row] = (uint32_t)fmaf(ve.z, as.z, QBIAS);
      Es[(dbase + 3) * TE + row] = (uint32_t)fmaf(ve.w, as.w, QBIAS);
    }
    __syncthreads();

    const uint4* Xs4 = reinterpret_cast<const uint4*>(Xs);
    const uint4* Es4 = reinterpret_cast<const uint4*>(Es);
#pragma unroll 4
    for (int d = 0; d < KC; ++d) {
      // Xs4: 4 distinct addrs/wave (16-lane broadcast); Es4: 16 consecutive
      // addrs spanning all 32 banks -> both conflict-free.
      uint4 xv = Xs4[d * (TB / 4) + ty];
      uint4 ev = Es4[d * (TE / 4) + tx];
      SAD(acc[0][0], xv.x, ev.x); SAD(acc[0][1], xv.x, ev.y);
      SAD(acc[0][2], xv.x, ev.z); SAD(acc[0][3], xv.x, ev.w);
      SAD(acc[1][0], xv.y, ev.x); SAD(acc[1][1], xv.y, ev.y);
      SAD(acc[1][2], xv.y, ev.z); SAD(acc[1][3], xv.y, ev.w);
      SAD(acc[2][0], xv.z, ev.x); SAD(acc[2][1], xv.z, ev.y);
      SAD(acc[2][2], xv.z, ev.z); SAD(acc[2][3], xv.z, ev.w);
      SAD(acc[3][0], xv.w, ev.x); SAD(acc[3][1], xv.w, ev.y);
      SAD(acc[3][2], xv.w, ev.z); SAD(acc[3][3], xv.w, ev.w);
    }
  }

  // Epilogue: dist = acc / 2^24; out = exp(-C*dist) = __expf(KEXP * acc)
#pragma unroll
  for (int j = 0; j < 4; ++j) {
    int b = b0 + 4 * ty + j;
    float4 o;
    o.x = __expf(KEXP * (float)acc[j][0]);
    o.y = __expf(KEXP * (float)acc[j][1]);
    o.z = __expf(KEXP * (float)acc[j][2]);
    o.w = __expf(KEXP * (float)acc[j][3]);
    reinterpret_cast<float4*>(out + (size_t)b * NE + e0)[tx] = o;
  }
}

extern "C" void kernel_launch(void* const* d_in, const int* in_sizes, int n_in,
                              void* d_out, int out_size, void* d_ws, size_t ws_size,
                              hipStream_t stream) {
  const float* X = (const float*)d_in[0];   // inputs    (2048,128)
  const float* E = (const float*)d_in[1];   // exemplars (2048,128)
  const float* A = (const float*)d_in[2];   // attn      (128,)
  float* out = (float*)d_out;               // (2048,2048)

  dim3 grid(NE / TE, BATCH / TB);           // (32,32) = 1024 blocks = 4/CU
  dim3 block(256);
  alcove_rbf_kernel<<<grid, block, 0, stream>>>(X, E, A, out);
}